// Round 2
// baseline (178.429 us; speedup 1.0000x reference)
//
#include <hip/hip_runtime.h>
#include <math.h>

#define DIM 1024
#define NB  256
#define NF  64

// ---------------- ws layout (total 1.283 MB, everything fully overwritten each call) ---
// thres : [0      , 4 KB)
// diag  : [4 KB   , 8 KB)
// dpart : [8 KB   , 264 KB)   64 x 1024 f32 partial column sums
// vmean : [264 KB , 264 KB + 1 MB)

// ---------------- A: thres[r] = mean + simw[r]*std (ddof=1) of sigmoid(emb[r,:]) -------
__global__ void kthres(const float* __restrict__ emb, const float* __restrict__ simw,
                       float* __restrict__ thres) {
    int r = blockIdx.x;          // 0..1023
    int t = threadIdx.x;         // 0..255, owns cols 4t..4t+3
    float4 e = *(const float4*)(emb + (size_t)r * DIM + t * 4);
    float w0 = 1.0f / (1.0f + expf(-e.x));
    float w1 = 1.0f / (1.0f + expf(-e.y));
    float w2 = 1.0f / (1.0f + expf(-e.z));
    float w3 = 1.0f / (1.0f + expf(-e.w));
    double s  = (double)w0 + w1 + w2 + w3;
    double sq = (double)w0*w0 + (double)w1*w1 + (double)w2*w2 + (double)w3*w3;
    #pragma unroll
    for (int off = 32; off > 0; off >>= 1) {
        s  += __shfl_down(s, off);
        sq += __shfl_down(sq, off);
    }
    __shared__ double ls[4], lq[4];
    int wid = t >> 6, lane = t & 63;
    if (lane == 0) { ls[wid] = s; lq[wid] = sq; }
    __syncthreads();
    if (t == 0) {
        double S = ls[0] + ls[1] + ls[2] + ls[3];
        double Q = lq[0] + lq[1] + lq[2] + lq[3];
        double mean = S / DIM;
        double var  = (Q - S * S / DIM) / (DIM - 1);
        if (var < 0.0) var = 0.0;
        thres[r] = (float)(mean + (double)simw[r] * sqrt(var));
    }
}

// ------- B1: per-block partial column sums of dlw (row-L2-normalized mask*w) ----------
__global__ void kdiagpart(const float* __restrict__ emb, const float* __restrict__ thres,
                          const float* __restrict__ tempw, float* __restrict__ dpart) {
    int bid = blockIdx.x;        // 0..63 -> rows 16*bid..+15
    int t   = threadIdx.x;       // 0..255, owns cols 4t..4t+3
    float et = expf(tempw[0]);
    float4 th = *(const float4*)(thres + t * 4);
    float a0 = 0.f, a1 = 0.f, a2 = 0.f, a3 = 0.f;
    __shared__ float red[4];
    int r0 = bid * 16;
    for (int rr = 0; rr < 16; ++rr) {
        int r = r0 + rr;
        float4 e = *(const float4*)(emb + (size_t)r * DIM + t * 4);
        float w0 = 1.0f / (1.0f + expf(-e.x));
        float w1 = 1.0f / (1.0f + expf(-e.y));
        float w2 = 1.0f / (1.0f + expf(-e.z));
        float w3 = 1.0f / (1.0f + expf(-e.w));
        float m0 = tanhf(expf(et * (w0 - th.x))) * w0;
        float m1 = tanhf(expf(et * (w1 - th.y))) * w1;
        float m2 = tanhf(expf(et * (w2 - th.z))) * w2;
        float m3 = tanhf(expf(et * (w3 - th.w))) * w3;
        float ss = m0*m0 + m1*m1 + m2*m2 + m3*m3;
        #pragma unroll
        for (int off = 32; off > 0; off >>= 1) ss += __shfl_down(ss, off);
        int wid = t >> 6, lane = t & 63;
        if (lane == 0) red[wid] = ss;
        __syncthreads();
        float rn = 1.0f / (sqrtf(red[0] + red[1] + red[2] + red[3]) + 1e-8f);
        a0 += m0 * rn; a1 += m1 * rn; a2 += m2 * rn; a3 += m3 * rn;
        __syncthreads();   // before red[] reuse next row
    }
    float* dst = dpart + (size_t)bid * DIM + t * 4;
    dst[0] = a0; dst[1] = a1; dst[2] = a2; dst[3] = a3;
}

// ------- B2: diag[c] = sum_b dpart[b][c]  (deterministic, no atomics) -----------------
__global__ void kdiagred(const float* __restrict__ dpart, float* __restrict__ diag) {
    int c = blockIdx.x * 256 + threadIdx.x;   // 4 blocks x 256
    float s = 0.f;
    #pragma unroll
    for (int b = 0; b < 64; ++b) s += dpart[(size_t)b * DIM + c];
    diag[c] = s;
}

// ------- C: vmean[j,d] = mean_f vid[j,f,d]  (the dominant 64 MB HBM read) -------------
__global__ void kvmean(const float* __restrict__ vid, float* __restrict__ vmean) {
    int j  = blockIdx.x;                 // 0..255
    int t  = threadIdx.x & 255;          // owns d = 4t..4t+3
    int fh = threadIdx.x >> 8;           // 0..3, f-range split
    const float* base = vid + (size_t)j * NF * DIM + (size_t)fh * 16 * DIM + t * 4;
    float4 a = {0.f, 0.f, 0.f, 0.f};
    #pragma unroll
    for (int f = 0; f < 16; ++f) {
        float4 v = *(const float4*)(base + (size_t)f * DIM);
        a.x += v.x; a.y += v.y; a.z += v.z; a.w += v.w;
    }
    __shared__ float4 lds[768];
    if (fh > 0) lds[(fh - 1) * 256 + t] = a;
    __syncthreads();
    if (fh == 0) {
        float4 b1 = lds[t], b2 = lds[256 + t], b3 = lds[512 + t];
        a.x = (a.x + b1.x + b2.x + b3.x) * (1.0f / 64.0f);
        a.y = (a.y + b1.y + b2.y + b3.y) * (1.0f / 64.0f);
        a.z = (a.z + b1.z + b2.z + b3.z) * (1.0f / 64.0f);
        a.w = (a.w + b1.w + b2.w + b3.w) * (1.0f / 64.0f);
        *(float4*)(vmean + (size_t)j * DIM + t * 4) = a;
    }
}

// ------- D: sim[i,j] = sum_d txt[i,d]*diag[d]*vmean[j,d]  -> directly into d_out ------
#define TK   128
#define PADK (TK + 4)
__global__ void kgemm32(const float* __restrict__ txt, const float* __restrict__ diag,
                        const float* __restrict__ vmean, float* __restrict__ out) {
    __shared__ float Tt[32][PADK];
    __shared__ float Vt[32][PADK];
    int bx = blockIdx.x;              // 0..63 -> 8x8 tiles of 32x32
    int i0 = (bx & 7) * 32, j0 = (bx >> 3) * 32;
    int t  = threadIdx.x;             // 0..255
    int tx = t & 15, ty = t >> 4;     // 16x16 threads, 2x2 outputs each
    float acc00 = 0.f, acc01 = 0.f, acc10 = 0.f, acc11 = 0.f;
    for (int kb = 0; kb < DIM; kb += TK) {
        #pragma unroll
        for (int p = 0; p < 4; ++p) {
            int fid = p * 256 + t;    // 0..1023
            int row = fid >> 5;       // 0..31
            int kq  = fid & 31;       // float4 index 0..31
            float4 a  = *(const float4*)(txt + (size_t)(i0 + row) * DIM + kb + kq * 4);
            float4 dg = *(const float4*)(diag + kb + kq * 4);
            a.x *= dg.x; a.y *= dg.y; a.z *= dg.z; a.w *= dg.w;
            *(float4*)&Tt[row][kq * 4] = a;
            float4 b = *(const float4*)(vmean + (size_t)(j0 + row) * DIM + kb + kq * 4);
            *(float4*)&Vt[row][kq * 4] = b;
        }
        __syncthreads();
        #pragma unroll
        for (int k4 = 0; k4 < TK / 4; ++k4) {
            float4 a0 = *(float4*)&Tt[ty * 2 + 0][k4 * 4];
            float4 a1 = *(float4*)&Tt[ty * 2 + 1][k4 * 4];
            float4 b0 = *(float4*)&Vt[tx * 2 + 0][k4 * 4];
            float4 b1 = *(float4*)&Vt[tx * 2 + 1][k4 * 4];
            acc00 = fmaf(a0.x, b0.x, acc00); acc00 = fmaf(a0.y, b0.y, acc00);
            acc00 = fmaf(a0.z, b0.z, acc00); acc00 = fmaf(a0.w, b0.w, acc00);
            acc01 = fmaf(a0.x, b1.x, acc01); acc01 = fmaf(a0.y, b1.y, acc01);
            acc01 = fmaf(a0.z, b1.z, acc01); acc01 = fmaf(a0.w, b1.w, acc01);
            acc10 = fmaf(a1.x, b0.x, acc10); acc10 = fmaf(a1.y, b0.y, acc10);
            acc10 = fmaf(a1.z, b0.z, acc10); acc10 = fmaf(a1.w, b0.w, acc10);
            acc11 = fmaf(a1.x, b1.x, acc11); acc11 = fmaf(a1.y, b1.y, acc11);
            acc11 = fmaf(a1.z, b1.z, acc11); acc11 = fmaf(a1.w, b1.w, acc11);
        }
        __syncthreads();
    }
    out[(size_t)(i0 + ty * 2 + 0) * NB + j0 + tx * 2 + 0] = acc00;
    out[(size_t)(i0 + ty * 2 + 0) * NB + j0 + tx * 2 + 1] = acc01;
    out[(size_t)(i0 + ty * 2 + 1) * NB + j0 + tx * 2 + 0] = acc10;
    out[(size_t)(i0 + ty * 2 + 1) * NB + j0 + tx * 2 + 1] = acc11;
}

// ------- E: row-wise L2 normalize d_out in place --------------------------------------
__global__ void knorm(float* __restrict__ out) {
    int i = blockIdx.x;    // row
    int j = threadIdx.x;   // col
    float s = out[(size_t)i * NB + j];
    float ss = s * s;
    #pragma unroll
    for (int off = 32; off > 0; off >>= 1) ss += __shfl_down(ss, off);
    __shared__ float red[4];
    int wid = j >> 6, lane = j & 63;
    if (lane == 0) red[wid] = ss;
    __syncthreads();
    float norm = sqrtf(red[0] + red[1] + red[2] + red[3]);
    out[(size_t)i * NB + j] = s / (norm + 1e-8f);
}

extern "C" void kernel_launch(void* const* d_in, const int* in_sizes, int n_in,
                              void* d_out, int out_size, void* d_ws, size_t ws_size,
                              hipStream_t stream) {
    const float* txt   = (const float*)d_in[0];   // [256,1024]
    const float* vid   = (const float*)d_in[1];   // [256,64,1024]
    const float* emb   = (const float*)d_in[2];   // [1024,1024]
    const float* simw  = (const float*)d_in[3];   // [1,1024]
    const float* tempw = (const float*)d_in[4];   // [1,1]
    float* out = (float*)d_out;                   // [256,256]

    char* ws = (char*)d_ws;
    float* thres = (float*)(ws);                  // 4 KB
    float* diag  = (float*)(ws + 4096);           // 4 KB
    float* dpart = (float*)(ws + 8192);           // 256 KB
    float* vmean = (float*)(ws + 8192 + 262144);  // 1 MB   (total 1.283 MB)

    kvmean   <<<256,  1024, 0, stream>>>(vid, vmean);          // dominant HBM read
    kthres   <<<1024, 256,  0, stream>>>(emb, simw, thres);
    kdiagpart<<<64,   256,  0, stream>>>(emb, thres, tempw, dpart);
    kdiagred <<<4,    256,  0, stream>>>(dpart, diag);
    kgemm32  <<<64,   256,  0, stream>>>(txt, diag, vmean, out);
    knorm    <<<256,  256,  0, stream>>>(out);
}